// Round 8
// baseline (209.141 us; speedup 1.0000x reference)
//
#include <hip/hip_runtime.h>
#include <math.h>
#include <float.h>

// DeepSeek V3 router, round 8.
// Diagnosis R6/R7: kernel was LDS-read-throughput-bound (ds_read_b128 pipe
// ~2.4x over matrix pipe). Fix: B never touches LDS. convert_w pre-packs the
// two fp16 W planes in MFMA-fragment order (1024B records, lane l at l*16),
// so the GEMM loads B frags global->reg fully coalesced; B slice per splitK
// is 1.83MB -> L2-resident, with ks pinned per XCD so each XCD's L2 keeps
// its own slice. Block = 32 rows x all 256 cols (4 waves x wave-tile 32x64);
// A staged through an 8KB LDS dbuf (reads now 16 b128/block-step vs 96).
// Numerics: R7's validated single-accumulator 3-pass split-fp16:
//   acc += a0*b0; acc += (a1*2^-6)*(b0*2^-5); acc += (a0*2^-5)*b3
// with a0=fp16(x), a1=fp16(res_x*2048), b0=fp16(256w), b3=fp16(res_w*8192).

#define TDIM 8192
#define DDIM 7168
#define EDIM 256
#define KT   (DDIM / 32)   // 224 k-tiles

typedef _Float16 h8 __attribute__((ext_vector_type(8)));
typedef _Float16 h4 __attribute__((ext_vector_type(4)));
typedef float f4 __attribute__((ext_vector_type(4)));

// ---------------- K1: W -> fragment-packed fp16 planes ----------------
// Packed layout (halfs): Bp[((p*16 + cf)*KT + ktg)*512 + lane*8]
//   cf = e>>4, lane = (e&15) + (((k>>3)&3)<<4), 8 consecutive k-halfs.
__global__ __launch_bounds__(256)
void convert_w(const float* __restrict__ W, _Float16* __restrict__ Bp)
{
    __shared__ _Float16 l0[64][80];
    __shared__ _Float16 l1[64][80];
    const int t = threadIdx.x;
    const int kt = blockIdx.x * 64;
    const int et = blockIdx.y * 64;
#pragma unroll
    for (int i = 0; i < 16; ++i) {
        const int kr = (t >> 6) * 16 + i;
        const int ec = t & 63;
        const float w = W[(size_t)(kt + kr) * EDIM + et + ec] * 256.f;
        const _Float16 h0 = (_Float16)w;
        const _Float16 h1 = (_Float16)((w - (float)h0) * 32.f);
        l0[ec][kr] = h0;
        l1[ec][kr] = h1;
    }
    __syncthreads();
#pragma unroll
    for (int j = 0; j < 2; ++j) {
        const int er = t >> 2;                    // e within tile 0..63
        const int kc = ((t & 3) + 4 * j) * 8;     // k within tile, /8
        const int e  = et + er;
        const int k  = kt + kc;
        const int laneI = (e & 15) + (((k >> 3) & 3) << 4);
        const uint4 v0 = *(const uint4*)&l0[er][kc];
        const uint4 v1 = *(const uint4*)&l1[er][kc];
        const size_t o0 =
            ((size_t)((0 * 16 + (e >> 4)) * KT + (k >> 5))) * 512 + laneI * 8;
        const size_t o1 =
            ((size_t)((1 * 16 + (e >> 4)) * KT + (k >> 5))) * 512 + laneI * 8;
        *(uint4*)&Bp[o0] = v0;
        *(uint4*)&Bp[o1] = v1;
    }
}

// ---------------- K2: single-acc split-fp16 MFMA GEMM, B from global ------
__global__ __launch_bounds__(256, 3)
void gemm_mfma(const float* __restrict__ X,
               const _Float16* __restrict__ Bp,
               float* __restrict__ P,
               int splitK, int kLen)
{
    __shared__ _Float16 sA[2][2][32][32];   // 8 KB: [buf][plane][row][k-halfs]

    const int t    = threadIdx.x;
    const int lane = t & 63;
    const int w    = t >> 6;                // wave 0..3 -> cols w*64..+63

    // ks pinned per XCD so each XCD's L2 holds one 1.83MB B slice.
    const int xcd = blockIdx.x & 7;
    const int j   = blockIdx.x >> 3;
    const int ks  = xcd % splitK;
    const int mb  = j * (8 / splitK) + xcd / splitK;
    const int m0  = mb * 32;
    const int kbeg = ks * kLen;
    const int nt   = kLen >> 5;
    const int ktg0 = kbeg >> 5;

    f4 acc[2][4];
#pragma unroll
    for (int i = 0; i < 2; ++i)
#pragma unroll
        for (int jj = 0; jj < 4; ++jj) acc[i][jj] = (f4)0.f;

    // A staging: thread -> row t>>3, float4 at granule (t>>1)&3, half t&1
    const int rowA  = t >> 3;
    const float* xg = X + (size_t)(m0 + rowA) * DDIM + kbeg + (t & 7) * 4;
    const int slotA = ((((t >> 1) & 3) ^ ((rowA >> 2) & 3)) << 3) | ((t & 1) << 2);

    // B fragment base: wave w covers cf = w*4+f
    const _Float16* bbase =
        Bp + ((size_t)(w * 4) * KT + ktg0) * 512 + lane * 8;

    float4 va;

#define LOADA(kb) { va = *(const float4*)(xg + (kb)); }

#define WRITEA(buf)                                                           \
    {                                                                         \
        h4 p0, p1;                                                            \
        const float xv[4] = {va.x, va.y, va.z, va.w};                         \
        _Pragma("unroll")                                                     \
        for (int q = 0; q < 4; ++q) {                                         \
            const _Float16 h0 = (_Float16)xv[q];                              \
            p0[q] = h0;                                                       \
            p1[q] = (_Float16)((xv[q] - (float)h0) * 2048.f);                 \
        }                                                                     \
        *(h4*)&sA[buf][0][rowA][slotA] = p0;                                  \
        *(h4*)&sA[buf][1][rowA][slotA] = p1;                                  \
    }

#define BLOAD(RB, TI)                                                         \
    {                                                                         \
        _Pragma("unroll")                                                     \
        for (int p = 0; p < 2; ++p)                                           \
        _Pragma("unroll")                                                     \
        for (int f = 0; f < 4; ++f)                                           \
            RB[p][f] = *(const h8*)(bbase +                                   \
                ((size_t)(p * 16 + f) * KT + (TI)) * 512);                    \
    }

#define AREAD(CUR)                                                            \
    {                                                                         \
        _Pragma("unroll")                                                     \
        for (int h = 0; h < 2; ++h) {                                         \
            a0[h] = *(const h8*)&sA[CUR][0][h * 16 + (lane & 15)][kqs];       \
            a1[h] = *(const h8*)&sA[CUR][1][h * 16 + (lane & 15)][kqs];       \
        }                                                                     \
    }

#define MFMA3(RB)                                                             \
    {                                                                         \
        __builtin_amdgcn_s_setprio(1);                                        \
        _Pragma("unroll")                                                     \
        for (int h = 0; h < 2; ++h)                                           \
        _Pragma("unroll")                                                     \
        for (int f = 0; f < 4; ++f)                                           \
            acc[h][f] = __builtin_amdgcn_mfma_f32_16x16x32_f16(               \
                a0[h], RB[0][f], acc[h][f], 0, 0, 0);                         \
        _Pragma("unroll")                                                     \
        for (int f = 0; f < 4; ++f)                                           \
        _Pragma("unroll")                                                     \
        for (int q = 0; q < 8; ++q) RB[0][f][q] *= S5;                        \
        _Pragma("unroll")                                                     \
        for (int h = 0; h < 2; ++h)                                           \
        _Pragma("unroll")                                                     \
        for (int q = 0; q < 8; ++q) a1[h][q] *= S6;                           \
        _Pragma("unroll")                                                     \
        for (int h = 0; h < 2; ++h)                                           \
        _Pragma("unroll")                                                     \
        for (int f = 0; f < 4; ++f)                                           \
            acc[h][f] = __builtin_amdgcn_mfma_f32_16x16x32_f16(               \
                a1[h], RB[0][f], acc[h][f], 0, 0, 0);                         \
        _Pragma("unroll")                                                     \
        for (int h = 0; h < 2; ++h)                                           \
        _Pragma("unroll")                                                     \
        for (int q = 0; q < 8; ++q) a0[h][q] *= S5;                           \
        _Pragma("unroll")                                                     \
        for (int h = 0; h < 2; ++h)                                           \
        _Pragma("unroll")                                                     \
        for (int f = 0; f < 4; ++f)                                           \
            acc[h][f] = __builtin_amdgcn_mfma_f32_16x16x32_f16(               \
                a0[h], RB[1][f], acc[h][f], 0, 0, 0);                         \
        __builtin_amdgcn_s_setprio(0);                                        \
    }

    const int kqs = (((lane >> 4) ^ (lane >> 2)) & 3) << 3;
    const _Float16 S5 = (_Float16)0.03125f;     // 2^-5
    const _Float16 S6 = (_Float16)0.015625f;    // 2^-6

    h8 bEven[2][4], bOdd[2][4];

    // prologue: A(0) -> sA[0]; B(0) -> bEven
    LOADA(0);
    BLOAD(bEven, 0);
    WRITEA(0);                         // compiler waits va, B stays in flight
    asm volatile("s_waitcnt lgkmcnt(0)" ::: "memory");
    __builtin_amdgcn_s_barrier();

    for (int ti = 0; ti < nt; ti += 2) {
        {   // even phase: tile ti, sA[0], bEven
            h8 a0[2], a1[2];
            const bool hn = (ti + 1) < nt;
            if (hn) { LOADA((ti + 1) * 32); BLOAD(bOdd, ti + 1); }
            AREAD(0);
            MFMA3(bEven);
            if (hn) WRITEA(1);
            asm volatile("s_waitcnt lgkmcnt(0)" ::: "memory");
            __builtin_amdgcn_s_barrier();
        }
        {   // odd phase: tile ti+1, sA[1], bOdd
            h8 a0[2], a1[2];
            const bool hn = (ti + 2) < nt;
            if (hn) { LOADA((ti + 2) * 32); BLOAD(bEven, ti + 2); }
            AREAD(1);
            MFMA3(bOdd);
            if (hn) WRITEA(0);
            asm volatile("s_waitcnt lgkmcnt(0)" ::: "memory");
            __builtin_amdgcn_s_barrier();
        }
    }

    // epilogue: logit = acc / 256
    const float s0 = 1.f / 256.f;
#pragma unroll
    for (int h = 0; h < 2; ++h)
#pragma unroll
        for (int f = 0; f < 4; ++f) {
            const int gr = m0 + h * 16 + (lane >> 4) * 4;
            const int gc = w * 64 + f * 16 + (lane & 15);
#pragma unroll
            for (int r = 0; r < 4; ++r)
                P[((size_t)ks * TDIM + gr + r) * EDIM + gc] = acc[h][f][r] * s0;
        }
}

// ---------------- K3: reduce + sigmoid + grouped top-k route ----------------
__global__ __launch_bounds__(256, 4)
void route_kernel(const float* __restrict__ P,
                  const float* __restrict__ B,
                  float* __restrict__ out,
                  int splitK)
{
    const int t    = threadIdx.x;
    const int lane = t & 63;
    const int wid  = t >> 6;
    const int tok0 = blockIdx.x * 32 + wid * 8;

    const float4 bv4 = *(const float4*)&B[lane * 4];
    const float bb[4] = {bv4.x, bv4.y, bv4.z, bv4.w};
    const int g = lane >> 3;

#pragma unroll
    for (int i = 0; i < 8; ++i) {
        const int tok = tok0 + i;
        float a[4] = {0.f, 0.f, 0.f, 0.f};
        for (int ksl = 0; ksl < splitK; ++ksl) {
            const float4 pv =
                *(const float4*)&P[((size_t)ksl * TDIM + tok) * EDIM + lane * 4];
            a[0] += pv.x; a[1] += pv.y; a[2] += pv.z; a[3] += pv.w;
        }
        float v[4], s[4];
#pragma unroll
        for (int jq = 0; jq < 4; ++jq) {
            v[jq] = 1.f / (1.f + expf(-a[jq]));
            s[jq] = v[jq] + bb[jq];
        }
        float t1 = s[0], t2 = -FLT_MAX;
#pragma unroll
        for (int jq = 1; jq < 4; ++jq) {
            if (s[jq] > t1) { t2 = t1; t1 = s[jq]; }
            else if (s[jq] > t2) t2 = s[jq];
        }
#pragma unroll
        for (int d = 1; d < 8; d <<= 1) {
            float o1 = __shfl_xor(t1, d);
            float o2 = __shfl_xor(t2, d);
            float n1 = fmaxf(t1, o1);
            float n2 = fmaxf(fminf(t1, o1), fmaxf(t2, o2));
            t1 = n1; t2 = n2;
        }
        const float gsc = t1 + t2;
        float gs[8];
#pragma unroll
        for (int q = 0; q < 8; ++q) gs[q] = __shfl(gsc, q * 8);
        int gmask = 0;
#pragma unroll
        for (int it = 0; it < 4; ++it) {
            float bvv = -FLT_MAX; int bg = 0;
#pragma unroll
            for (int q = 0; q < 8; ++q) {
                const bool avail = ((gmask >> q) & 1) == 0;
                if (avail && gs[q] > bvv) { bvv = gs[q]; bg = q; }
            }
            gmask |= (1 << bg);
        }
        if (((gmask >> g) & 1) == 0) { s[0] = 0.f; s[1] = 0.f; s[2] = 0.f; s[3] = 0.f; }

        float wk[8]; int ik[8]; float wsum = 0.f;
#pragma unroll
        for (int it = 0; it < 8; ++it) {
            float bvv = s[0]; int bi = lane * 4; float bs = v[0];
#pragma unroll
            for (int jq = 1; jq < 4; ++jq)
                if (s[jq] > bvv) { bvv = s[jq]; bi = lane * 4 + jq; bs = v[jq]; }
#pragma unroll
            for (int d = 1; d < 64; d <<= 1) {
                float ov = __shfl_xor(bvv, d);
                int   oi = __shfl_xor(bi, d);
                float os = __shfl_xor(bs, d);
                if (ov > bvv || (ov == bvv && oi < bi)) { bvv = ov; bi = oi; bs = os; }
            }
            wk[it] = bs; ik[it] = bi; wsum += bs;
#pragma unroll
            for (int jq = 0; jq < 4; ++jq)
                if (bi == lane * 4 + jq) s[jq] = -FLT_MAX;
        }
        const float den = wsum + 1e-20f;
        if (lane == 0) {
#pragma unroll
            for (int q = 0; q < 8; ++q) {
                out[(size_t)tok * 8 + q] = wk[q] / den * 2.5f;
                out[(size_t)TDIM * 8 + (size_t)tok * 8 + q] = (float)ik[q];
            }
        }
    }
}

extern "C" void kernel_launch(void* const* d_in, const int* in_sizes, int n_in,
                              void* d_out, int out_size, void* d_ws, size_t ws_size,
                              hipStream_t stream)
{
    (void)in_sizes; (void)n_in; (void)out_size;
    const float* x    = (const float*)d_in[0];
    const float* kern = (const float*)d_in[1];
    const float* bias = (const float*)d_in[2];
    float* out = (float*)d_out;

    const size_t packedBytes = (size_t)2 * 16 * KT * 1024;   // 7.34 MB
    int splitK = 4;
    while (splitK > 1 &&
           (size_t)splitK * TDIM * EDIM * 4 + packedBytes > ws_size)
        splitK >>= 1;

    float* P = (float*)d_ws;
    _Float16* Bp = (_Float16*)((char*)d_ws + (size_t)splitK * TDIM * EDIM * 4);

    convert_w<<<dim3(DDIM / 64, EDIM / 64), 256, 0, stream>>>(kern, Bp);
    gemm_mfma<<<(TDIM / 32) * splitK, 256, 0, stream>>>(
        x, Bp, P, splitK, DDIM / splitK);
    route_kernel<<<TDIM / 32, 256, 0, stream>>>(P, bias, out, splitK);
}

// Round 9
// 168.262 us; speedup vs baseline: 1.2430x; 1.2430x over previous
//
#include <hip/hip_runtime.h>
#include <math.h>
#include <float.h>

// DeepSeek V3 router, round 9.
// Diagnosis R7/R8: 16x16x32 MFMA = 8 FLOP/operand-byte -> either LDS pipe
// (R7, 85B/cy) or VMEM pipe (R8, 64B/cy) saturates before the matrix pipe.
// Fix: 32x32x16 MFMA (16 FLOP/operand-byte, faster ubench) + operand traffic
// SPLIT across pipes: A via LDS (convert-on-write, swizzled), B via
// global->reg from fragment-packed planes (L2-resident slice per XCD).
// Per block-step: matrix 775cy > VMEM 625 > LDS 470 -> matrix-bound.
// Numerics: validated single-accumulator 3-pass split-fp16 (R7/R8):
//   acc += a0*b0; acc += (a1*2^-6)*(b0*2^-5); acc += (a0*2^-5)*b3
//   a0=fp16(x), a1=fp16(res_x*2048), b0=fp16(256w), b3=fp16(res_w256*32).

#define TDIM 8192
#define DDIM 7168
#define EDIM 256
#define KT   (DDIM / 32)   // 224 k-tiles of 32

typedef _Float16 h8 __attribute__((ext_vector_type(8)));
typedef float f16v __attribute__((ext_vector_type(16)));

// ---------------- K1: W -> 32x32x16-fragment-packed fp16 planes ------------
// Fragment lane l <-> (e = l&31, k = kf*16 + (l>>5)*8 + j).
// Offset(halfs) = (((p*8 + cf)*KT + kt)*2 + kf)*512 + lane*8,
//   cf = e>>5, kt = k>>5, kf = (k>>4)&1, lane = (e&31) + 32*((k>>3)&1).
__global__ __launch_bounds__(256)
void convert_w(const float* __restrict__ W, _Float16* __restrict__ Bp)
{
    __shared__ _Float16 l0[64][80];
    __shared__ _Float16 l1[64][80];
    const int t = threadIdx.x;
    const int kt = blockIdx.x * 64;
    const int et = blockIdx.y * 64;
#pragma unroll
    for (int i = 0; i < 16; ++i) {
        const int kr = (t >> 6) * 16 + i;
        const int ec = t & 63;
        const float w = W[(size_t)(kt + kr) * EDIM + et + ec] * 256.f;
        const _Float16 h0 = (_Float16)w;
        const _Float16 h1 = (_Float16)((w - (float)h0) * 32.f);
        l0[ec][kr] = h0;
        l1[ec][kr] = h1;
    }
    __syncthreads();
#pragma unroll
    for (int j = 0; j < 2; ++j) {
        const int er = t >> 2;                    // e within tile
        const int kc = ((t & 3) + 4 * j) * 8;     // k within tile (mult of 8)
        const int e  = et + er;
        const int k  = kt + kc;
        const int cf   = e >> 5;
        const int lane = (e & 31) + 32 * ((k >> 3) & 1);
        const int kf   = (k >> 4) & 1;
        const int ktl  = k >> 5;
        const uint4 v0 = *(const uint4*)&l0[er][kc];
        const uint4 v1 = *(const uint4*)&l1[er][kc];
        const size_t o0 = (((size_t)(0 * 8 + cf) * KT + ktl) * 2 + kf) * 512 + lane * 8;
        const size_t o1 = (((size_t)(1 * 8 + cf) * KT + ktl) * 2 + kf) * 512 + lane * 8;
        *(uint4*)&Bp[o0] = v0;
        *(uint4*)&Bp[o1] = v1;
    }
}

// ---------------- K2: 32x32x16 split-fp16 GEMM, A in LDS / B from L2 -------
__global__ __launch_bounds__(256, 2)
void gemm_mfma(const float* __restrict__ X,
               const _Float16* __restrict__ Bp,
               float* __restrict__ P,
               int splitK, int kLen)
{
    __shared__ _Float16 sA[2][2][64][32];   // 16 KB: [buf][plane][row][halfs]

    const int t    = threadIdx.x;
    const int lane = t & 63;
    const int w    = t >> 6;                // wave 0..3 -> cols w*64..+63

    // XCD pinning: xcd = bid&7; ks = xcd&3 (two XCDs per ks slice, 1.83MB/L2)
    const int xcd = blockIdx.x & 7;
    const int jb  = blockIdx.x >> 3;
    const int ks  = xcd & 3;
    const int mb  = jb * 2 + (xcd >> 2);
    const int m0  = mb * 64;
    const int kbeg = ks * kLen;
    const int nt   = kLen >> 5;
    const int ktg0 = kbeg >> 5;

    f16v acc[2][2];
#pragma unroll
    for (int h = 0; h < 2; ++h)
#pragma unroll
        for (int n = 0; n < 2; ++n) acc[h][n] = (f16v)0.f;

    // A staging: thread -> row t>>2 (0..63), granule g=t&3 (8 floats)
    const int rowA  = t >> 2;
    const int gA    = t & 3;
    const float* xg = X + (size_t)(m0 + rowA) * DDIM + kbeg + gA * 8;
    const int slotA = (gA ^ ((rowA >> 2) & 3)) * 8;   // halfs

    // B fragment base (lane-coalesced packed records)
    const _Float16* bbase = Bp + lane * 8;

    float4 va0, va1;

#define LOADA(kb)                                                             \
    {                                                                         \
        va0 = *(const float4*)(xg + (kb));                                    \
        va1 = *(const float4*)(xg + (kb) + 4);                                \
    }

#define WRITEA(buf)                                                           \
    {                                                                         \
        h8 p0, p1;                                                            \
        const float xv[8] = {va0.x, va0.y, va0.z, va0.w,                      \
                             va1.x, va1.y, va1.z, va1.w};                     \
        _Pragma("unroll")                                                     \
        for (int q = 0; q < 8; ++q) {                                         \
            const _Float16 h0 = (_Float16)xv[q];                              \
            p0[q] = h0;                                                       \
            p1[q] = (_Float16)((xv[q] - (float)h0) * 2048.f);                 \
        }                                                                     \
        *(h8*)&sA[buf][0][rowA][slotA] = p0;                                  \
        *(h8*)&sA[buf][1][rowA][slotA] = p1;                                  \
    }

    // RB[p][n][kf]
#define BLOAD(RB, TI)                                                         \
    {                                                                         \
        _Pragma("unroll")                                                     \
        for (int p = 0; p < 2; ++p)                                           \
        _Pragma("unroll")                                                     \
        for (int n = 0; n < 2; ++n)                                           \
        _Pragma("unroll")                                                     \
        for (int kf = 0; kf < 2; ++kf)                                        \
            RB[p][n][kf] = *(const h8*)(bbase +                               \
                (((size_t)(p * 8 + w * 2 + n) * KT + ktg0 + (TI)) * 2 + kf) * 512); \
    }

    // a0/a1[h][kf]: row = h*32 + (lane&31), granule = (lane>>5) + 2*kf
#define AREAD(CUR)                                                           \
    {                                                                         \
        _Pragma("unroll")                                                     \
        for (int h = 0; h < 2; ++h)                                           \
        _Pragma("unroll")                                                     \
        for (int kf = 0; kf < 2; ++kf) {                                      \
            const int rr = h * 32 + (lane & 31);                              \
            const int sl = (((lane >> 5) + 2 * kf) ^ ((rr >> 2) & 3)) * 8;    \
            a0[h][kf] = *(const h8*)&sA[CUR][0][rr][sl];                      \
            a1[h][kf] = *(const h8*)&sA[CUR][1][rr][sl];                      \
        }                                                                     \
    }

#define MFMA3(RB)                                                             \
    {                                                                         \
        __builtin_amdgcn_s_setprio(1);                                        \
        _Pragma("unroll")                                                     \
        for (int h = 0; h < 2; ++h)                                           \
        _Pragma("unroll")                                                     \
        for (int n = 0; n < 2; ++n)                                           \
        _Pragma("unroll")                                                     \
        for (int kf = 0; kf < 2; ++kf)                                        \
            acc[h][n] = __builtin_amdgcn_mfma_f32_32x32x16_f16(               \
                a0[h][kf], RB[0][n][kf], acc[h][n], 0, 0, 0);                 \
        _Pragma("unroll")                                                     \
        for (int n = 0; n < 2; ++n)                                           \
        _Pragma("unroll")                                                     \
        for (int kf = 0; kf < 2; ++kf)                                        \
        _Pragma("unroll")                                                     \
        for (int q = 0; q < 8; ++q) RB[0][n][kf][q] *= S5;                    \
        _Pragma("unroll")                                                     \
        for (int h = 0; h < 2; ++h)                                           \
        _Pragma("unroll")                                                     \
        for (int kf = 0; kf < 2; ++kf)                                        \
        _Pragma("unroll")                                                     \
        for (int q = 0; q < 8; ++q) a1[h][kf][q] *= S6;                       \
        _Pragma("unroll")                                                     \
        for (int h = 0; h < 2; ++h)                                           \
        _Pragma("unroll")                                                     \
        for (int n = 0; n < 2; ++n)                                           \
        _Pragma("unroll")                                                     \
        for (int kf = 0; kf < 2; ++kf)                                        \
            acc[h][n] = __builtin_amdgcn_mfma_f32_32x32x16_f16(               \
                a1[h][kf], RB[0][n][kf], acc[h][n], 0, 0, 0);                 \
        _Pragma("unroll")                                                     \
        for (int h = 0; h < 2; ++h)                                           \
        _Pragma("unroll")                                                     \
        for (int kf = 0; kf < 2; ++kf)                                        \
        _Pragma("unroll")                                                     \
        for (int q = 0; q < 8; ++q) a0[h][kf][q] *= S5;                       \
        _Pragma("unroll")                                                     \
        for (int h = 0; h < 2; ++h)                                           \
        _Pragma("unroll")                                                     \
        for (int n = 0; n < 2; ++n)                                           \
        _Pragma("unroll")                                                     \
        for (int kf = 0; kf < 2; ++kf)                                        \
            acc[h][n] = __builtin_amdgcn_mfma_f32_32x32x16_f16(               \
                a0[h][kf], RB[1][n][kf], acc[h][n], 0, 0, 0);                 \
        __builtin_amdgcn_s_setprio(0);                                        \
    }

    const _Float16 S5 = (_Float16)0.03125f;     // 2^-5
    const _Float16 S6 = (_Float16)0.015625f;    // 2^-6

    h8 bE[2][2][2], bO[2][2][2];

    // prologue
    LOADA(0);
    BLOAD(bE, 0);
    WRITEA(0);                 // waits va; B loads stay in flight
    asm volatile("s_waitcnt lgkmcnt(0)" ::: "memory");
    __builtin_amdgcn_s_barrier();

    for (int ti = 0; ti < nt; ti += 2) {
        {   // even: tile ti, sA[0], bE
            h8 a0[2][2], a1[2][2];
            const bool hn = (ti + 1) < nt;
            if (hn) { LOADA((ti + 1) * 32); BLOAD(bO, ti + 1); }
            AREAD(0);
            MFMA3(bE);
            if (hn) WRITEA(1);
            asm volatile("s_waitcnt lgkmcnt(0)" ::: "memory");
            __builtin_amdgcn_s_barrier();
        }
        {   // odd: tile ti+1, sA[1], bO
            h8 a0[2][2], a1[2][2];
            const bool hn = (ti + 2) < nt;
            if (hn) { LOADA((ti + 2) * 32); BLOAD(bE, ti + 2); }
            AREAD(1);
            MFMA3(bO);
            if (hn) WRITEA(0);
            asm volatile("s_waitcnt lgkmcnt(0)" ::: "memory");
            __builtin_amdgcn_s_barrier();
        }
    }

    // epilogue: logit = acc / 256; C/D: col=lane&31, row=(r&3)+8*(r>>2)+4*(lane>>5)
    const float s0 = 1.f / 256.f;
#pragma unroll
    for (int h = 0; h < 2; ++h)
#pragma unroll
        for (int n = 0; n < 2; ++n)
#pragma unroll
            for (int r = 0; r < 16; ++r) {
                const int row = (r & 3) + 8 * (r >> 2) + 4 * (lane >> 5);
                const int gr  = m0 + h * 32 + row;
                const int gc  = w * 64 + n * 32 + (lane & 31);
                P[((size_t)ks * TDIM + gr) * EDIM + gc] = acc[h][n][r] * s0;
            }
}

// ---------------- K3: reduce + sigmoid + grouped top-k route ----------------
__global__ __launch_bounds__(256, 4)
void route_kernel(const float* __restrict__ P,
                  const float* __restrict__ B,
                  float* __restrict__ out,
                  int splitK)
{
    const int t    = threadIdx.x;
    const int lane = t & 63;
    const int wid  = t >> 6;
    const int tok0 = blockIdx.x * 32 + wid * 8;

    const float4 bv4 = *(const float4*)&B[lane * 4];
    const float bb[4] = {bv4.x, bv4.y, bv4.z, bv4.w};
    const int g = lane >> 3;

#pragma unroll
    for (int i = 0; i < 8; ++i) {
        const int tok = tok0 + i;
        float a[4] = {0.f, 0.f, 0.f, 0.f};
        for (int ksl = 0; ksl < splitK; ++ksl) {
            const float4 pv =
                *(const float4*)&P[((size_t)ksl * TDIM + tok) * EDIM + lane * 4];
            a[0] += pv.x; a[1] += pv.y; a[2] += pv.z; a[3] += pv.w;
        }
        float v[4], s[4];
#pragma unroll
        for (int jq = 0; jq < 4; ++jq) {
            v[jq] = 1.f / (1.f + expf(-a[jq]));
            s[jq] = v[jq] + bb[jq];
        }
        float t1 = s[0], t2 = -FLT_MAX;
#pragma unroll
        for (int jq = 1; jq < 4; ++jq) {
            if (s[jq] > t1) { t2 = t1; t1 = s[jq]; }
            else if (s[jq] > t2) t2 = s[jq];
        }
#pragma unroll
        for (int d = 1; d < 8; d <<= 1) {
            float o1 = __shfl_xor(t1, d);
            float o2 = __shfl_xor(t2, d);
            float n1 = fmaxf(t1, o1);
            float n2 = fmaxf(fminf(t1, o1), fmaxf(t2, o2));
            t1 = n1; t2 = n2;
        }
        const float gsc = t1 + t2;
        float gs[8];
#pragma unroll
        for (int q = 0; q < 8; ++q) gs[q] = __shfl(gsc, q * 8);
        int gmask = 0;
#pragma unroll
        for (int it = 0; it < 4; ++it) {
            float bvv = -FLT_MAX; int bg = 0;
#pragma unroll
            for (int q = 0; q < 8; ++q) {
                const bool avail = ((gmask >> q) & 1) == 0;
                if (avail && gs[q] > bvv) { bvv = gs[q]; bg = q; }
            }
            gmask |= (1 << bg);
        }
        if (((gmask >> g) & 1) == 0) { s[0] = 0.f; s[1] = 0.f; s[2] = 0.f; s[3] = 0.f; }

        float wk[8]; int ik[8]; float wsum = 0.f;
#pragma unroll
        for (int it = 0; it < 8; ++it) {
            float bvv = s[0]; int bi = lane * 4; float bs = v[0];
#pragma unroll
            for (int jq = 1; jq < 4; ++jq)
                if (s[jq] > bvv) { bvv = s[jq]; bi = lane * 4 + jq; bs = v[jq]; }
#pragma unroll
            for (int d = 1; d < 64; d <<= 1) {
                float ov = __shfl_xor(bvv, d);
                int   oi = __shfl_xor(bi, d);
                float os = __shfl_xor(bs, d);
                if (ov > bvv || (ov == bvv && oi < bi)) { bvv = ov; bi = oi; bs = os; }
            }
            wk[it] = bs; ik[it] = bi; wsum += bs;
#pragma unroll
            for (int jq = 0; jq < 4; ++jq)
                if (bi == lane * 4 + jq) s[jq] = -FLT_MAX;
        }
        const float den = wsum + 1e-20f;
        if (lane == 0) {
#pragma unroll
            for (int q = 0; q < 8; ++q) {
                out[(size_t)tok * 8 + q] = wk[q] / den * 2.5f;
                out[(size_t)TDIM * 8 + (size_t)tok * 8 + q] = (float)ik[q];
            }
        }
    }
}

extern "C" void kernel_launch(void* const* d_in, const int* in_sizes, int n_in,
                              void* d_out, int out_size, void* d_ws, size_t ws_size,
                              hipStream_t stream)
{
    (void)in_sizes; (void)n_in; (void)out_size;
    const float* x    = (const float*)d_in[0];
    const float* kern = (const float*)d_in[1];
    const float* bias = (const float*)d_in[2];
    float* out = (float*)d_out;

    const size_t packedBytes = (size_t)2 * 8 * KT * 2 * 512 * 2;   // 7.34 MB
    int splitK = 4;
    while (splitK > 1 &&
           (size_t)splitK * TDIM * EDIM * 4 + packedBytes > ws_size)
        splitK >>= 1;

    float* P = (float*)d_ws;
    _Float16* Bp = (_Float16*)((char*)d_ws + (size_t)splitK * TDIM * EDIM * 4);

    convert_w<<<dim3(DDIM / 64, EDIM / 64), 256, 0, stream>>>(kern, Bp);
    gemm_mfma<<<(TDIM / 64) * splitK, 256, 0, stream>>>(
        x, Bp, P, splitK, DDIM / splitK);
    route_kernel<<<TDIM / 32, 256, 0, stream>>>(P, bias, out, splitK);
}